// Round 24
// baseline (65.077 us; speedup 1.0000x reference)
//
#include <hip/hip_runtime.h>

// BeamDelay2AntFreq: (256,32,8,4,2,48) complex -> ifft4(V) -> ifft8(H) -> fft48(t),
// fftshifts folded into (-1)^{h+v+f}; ortho norm 1/sqrt(1536).
// OUTPUT: interleaved bf16 pairs IMAG FIRST: dword = im | (re<<16), (b,c,row,f) order.
// R24 = R23 with complex-interleaved LDS (float2 / ds_*_b64): every (re,im)
// scalar pair is one b64 op -> LDS wave-insts 576 -> 288 per block. Same
// mappings, same scalar-array idioms (scratch-safe), j-split phase B.

namespace {

constexpr int RP = 49;       // T row stride in float2 units; span 48 < 49 => rows wave-private
constexpr float NORM = 0.02551551815399144f;  // 1/sqrt(1536)
constexpr float R2  = 0.70710678f;            // 1/sqrt(2)
constexpr float C30 = 0.86602540f;            // cos(30)

constexpr float COS48[48] = {
  1.0f,        0.99144486f,  0.96592583f,  0.92387953f,  0.86602540f,  0.79335334f,
  0.70710678f, 0.60876143f,  0.5f,         0.38268343f,  0.25881905f,  0.13052619f,
  0.0f,       -0.13052619f, -0.25881905f, -0.38268343f, -0.5f,        -0.60876143f,
 -0.70710678f,-0.79335334f, -0.86602540f, -0.92387953f, -0.96592583f, -0.99144486f,
 -1.0f,       -0.99144486f, -0.96592583f, -0.92387953f, -0.86602540f, -0.79335334f,
 -0.70710678f,-0.60876143f, -0.5f,        -0.38268343f, -0.25881905f, -0.13052619f,
  0.0f,        0.13052619f,  0.25881905f,  0.38268343f,  0.5f,         0.60876143f,
  0.70710678f, 0.79335334f,  0.86602540f,  0.92387953f,  0.96592583f,  0.99144486f
};
constexpr float SIN48[48] = {
  0.0f,        0.13052619f,  0.25881905f,  0.38268343f,  0.5f,         0.60876143f,
  0.70710678f, 0.79335334f,  0.86602540f,  0.92387953f,  0.96592583f,  0.99144486f,
  1.0f,        0.99144486f,  0.96592583f,  0.92387953f,  0.86602540f,  0.79335334f,
  0.70710678f, 0.60876143f,  0.5f,         0.38268343f,  0.25881905f,  0.13052619f,
  0.0f,       -0.13052619f, -0.25881905f, -0.38268343f, -0.5f,        -0.60876143f,
 -0.70710678f,-0.79335334f, -0.86602540f, -0.92387953f, -0.96592583f, -0.99144486f,
 -1.0f,       -0.99144486f, -0.96592583f, -0.92387953f, -0.86602540f, -0.79335334f,
 -0.70710678f,-0.60876143f, -0.5f,        -0.38268343f, -0.25881905f, -0.13052619f
};

__device__ __forceinline__ unsigned bf16_rne(float x) {
  unsigned u = __float_as_uint(x);
  u += 0x7FFFu + ((u >> 16) & 1u);
  return u >> 16;
}

__global__ __launch_bounds__(256, 6)
void bd2af_kernel(const float* __restrict__ xr, const float* __restrict__ xi,
                  unsigned* __restrict__ out, int nbc) {
  __shared__ __align__(8) float2 T[64 * RP];   // X->T1->Y->S overlay, (re,im) pairs

  const int tid = threadIdx.x;
  const int bc = blockIdx.x;
  if (bc >= nbc) return;

  const float* gxr = xr + (size_t)bc * 3072;
  const float* gxi = xi + (size_t)bc * 3072;

  // ---- V phase: global -> reg, 4-pt inverse FFT (kernel i^{V v'}), write T1 ----
  {
    const int hq = tid >> 5;           // 0..7
    const int p  = (tid >> 4) & 1;
    const int tc = tid & 15;
    const int t0 = 3 * tc;
    const int rowb = hq * 8 + p;       // row = rowb + 2V
#pragma unroll
    for (int k = 0; k < 3; ++k) {
      const int tt = t0 + k;
      const float x0r = gxr[(rowb + 0) * 48 + tt], x0i = gxi[(rowb + 0) * 48 + tt];
      const float x1r = gxr[(rowb + 2) * 48 + tt], x1i = gxi[(rowb + 2) * 48 + tt];
      const float x2r = gxr[(rowb + 4) * 48 + tt], x2i = gxi[(rowb + 4) * 48 + tt];
      const float x3r = gxr[(rowb + 6) * 48 + tt], x3i = gxi[(rowb + 6) * 48 + tt];
      const float e0r = x0r + x2r, e0i = x0i + x2i;
      const float e1r = x0r - x2r, e1i = x0i - x2i;
      const float o0r = x1r + x3r, o0i = x1i + x3i;
      const float o1r = x1r - x3r, o1i = x1i - x3i;
      T[(rowb + 0) * RP + tt] = make_float2(e0r + o0r, e0i + o0i);
      T[(rowb + 2) * RP + tt] = make_float2(e1r - o1i, e1i + o1r);   // +i*o1
      T[(rowb + 4) * RP + tt] = make_float2(e0r - o0r, e0i - o0i);
      T[(rowb + 6) * RP + tt] = make_float2(e1r + o1i, e1i - o1r);   // -i*o1
    }
  }
  __syncthreads();

  // ---- H phase (128 threads): 8-pt inverse FFT in-place, with (-1)^{h'+v'} ----
  if (tid < 128) {
    const int vq = tid >> 5;           // 0..3
    const int p  = (tid >> 4) & 1;
    const int tc = tid & 15;
    const int t0 = 3 * tc;
    const int rowb = 2 * vq + p;       // row = rowb + 8H
    const float sgnE = (vq & 1) ? -1.f : 1.f;   // (-1)^{h'+vq}, h' even
    const float sgnO = -sgnE;                   // h' odd
#pragma unroll
    for (int k = 0; k < 3; ++k) {
      const int tt = t0 + k;
      const float2 v0 = T[(rowb +  0) * RP + tt];
      const float2 v1 = T[(rowb +  8) * RP + tt];
      const float2 v2 = T[(rowb + 16) * RP + tt];
      const float2 v3 = T[(rowb + 24) * RP + tt];
      const float2 v4 = T[(rowb + 32) * RP + tt];
      const float2 v5 = T[(rowb + 40) * RP + tt];
      const float2 v6 = T[(rowb + 48) * RP + tt];
      const float2 v7 = T[(rowb + 56) * RP + tt];
      const float e0r = v0.x + v4.x, e0i = v0.y + v4.y, e1r = v0.x - v4.x, e1i = v0.y - v4.y;
      const float o0r = v2.x + v6.x, o0i = v2.y + v6.y, o1r = v2.x - v6.x, o1i = v2.y - v6.y;
      const float E0r = e0r + o0r, E0i = e0i + o0i;
      const float E2r = e0r - o0r, E2i = e0i - o0i;
      const float E1r = e1r - o1i, E1i = e1i + o1r;   // e1 + i o1
      const float E3r = e1r + o1i, E3i = e1i - o1r;   // e1 - i o1
      const float f0r = v1.x + v5.x, f0i = v1.y + v5.y, f1r = v1.x - v5.x, f1i = v1.y - v5.y;
      const float g0r = v3.x + v7.x, g0i = v3.y + v7.y, g1r = v3.x - v7.x, g1i = v3.y - v7.y;
      const float O0r = f0r + g0r, O0i = f0i + g0i;
      const float O2r = f0r - g0r, O2i = f0i - g0i;
      const float O1r = f1r - g1i, O1i = f1i + g1r;
      const float O3r = f1r + g1i, O3i = f1i - g1r;
      const float W1r = R2 * (O1r - O1i), W1i = R2 * (O1r + O1i);
      const float W3r = R2 * (-O3r - O3i), W3i = R2 * (O3r - O3i);
      T[(rowb +  0) * RP + tt] = make_float2(sgnE * (E0r + O0r), sgnE * (E0i + O0i));
      T[(rowb + 32) * RP + tt] = make_float2(sgnE * (E0r - O0r), sgnE * (E0i - O0i));
      T[(rowb + 16) * RP + tt] = make_float2(sgnE * (E2r - O2i), sgnE * (E2i + O2r));
      T[(rowb + 48) * RP + tt] = make_float2(sgnE * (E2r + O2i), sgnE * (E2i - O2r));
      T[(rowb +  8) * RP + tt] = make_float2(sgnO * (E1r + W1r), sgnO * (E1i + W1i));
      T[(rowb + 40) * RP + tt] = make_float2(sgnO * (E1r - W1r), sgnO * (E1i - W1i));
      T[(rowb + 24) * RP + tt] = make_float2(sgnO * (E3r + W3r), sgnO * (E3i + W3i));
      T[(rowb + 56) * RP + tt] = make_float2(sgnO * (E3r - W3r), sgnO * (E3i - W3i));
    }
  }
  __syncthreads();

  // ---- Phase A: radix-12 DFT per (row, b); S[b][j] at T[r*RP + b*12 + j] ----
  // Rows wave-private (r = tid>>2) -> in-place overlay safe; B same-wave -> no barrier.
  {
    const int r = tid >> 2;
    const int b = tid & 3;
    float zr[12], zi[12];
#pragma unroll
    for (int a = 0; a < 12; ++a) {
      const float2 v = T[r * RP + 4 * a + b];
      zr[a] = v.x;
      zi[a] = v.y;
    }
    float h0r[3], h0i[3], h1r[3], h1i[3], h2r[3], h2i[3], h3r[3], h3i[3];
#pragma unroll
    for (int a2 = 0; a2 < 3; ++a2) {
      const float e0r = zr[a2] + zr[a2 + 6], e0i = zi[a2] + zi[a2 + 6];
      const float e1r = zr[a2] - zr[a2 + 6], e1i = zi[a2] - zi[a2 + 6];
      const float o0r = zr[a2 + 3] + zr[a2 + 9], o0i = zi[a2 + 3] + zi[a2 + 9];
      const float o1r = zr[a2 + 3] - zr[a2 + 9], o1i = zi[a2 + 3] - zi[a2 + 9];
      h0r[a2] = e0r + o0r;  h0i[a2] = e0i + o0i;
      h2r[a2] = e0r - o0r;  h2i[a2] = e0i - o0i;
      h1r[a2] = e1r + o1i;  h1i[a2] = e1i - o1r;   // e1 - i o1 (forward)
      h3r[a2] = e1r - o1i;  h3i[a2] = e1i + o1r;   // e1 + i o1
    }
    {
      float a, bb;
      a = h1r[1]; bb = h1i[1];
      h1r[1] = C30 * a + 0.5f * bb;  h1i[1] = C30 * bb - 0.5f * a;
      a = h2r[1]; bb = h2i[1];
      h2r[1] = 0.5f * a + C30 * bb;  h2i[1] = 0.5f * bb - C30 * a;
      a = h3r[1]; bb = h3i[1];
      h3r[1] = bb;                   h3i[1] = -a;
      a = h1r[2]; bb = h1i[2];
      h1r[2] = 0.5f * a + C30 * bb;  h1i[2] = 0.5f * bb - C30 * a;
      a = h2r[2]; bb = h2i[2];
      h2r[2] = -0.5f * a + C30 * bb; h2i[2] = -0.5f * bb - C30 * a;
      h3r[2] = -h3r[2];              h3i[2] = -h3i[2];
    }
    float s_r[12], s_i[12];
#define DFT3(J1, HR, HI)                                                    \
    {                                                                       \
      const float tr_ = HR[1] + HR[2], ti_ = HI[1] + HI[2];                 \
      const float dr_ = HR[1] - HR[2], di_ = HI[1] - HI[2];                 \
      const float mr_ = HR[0] - 0.5f * tr_, mi_ = HI[0] - 0.5f * ti_;       \
      const float wr_ = C30 * dr_, wi_ = C30 * di_;                         \
      s_r[J1]     = HR[0] + tr_;  s_i[J1]     = HI[0] + ti_;                \
      s_r[J1 + 4] = mr_ + wi_;    s_i[J1 + 4] = mi_ - wr_;                  \
      s_r[J1 + 8] = mr_ - wi_;    s_i[J1 + 8] = mi_ + wr_;                  \
    }
    DFT3(0, h0r, h0i)
    DFT3(1, h1r, h1i)
    DFT3(2, h2r, h2i)
    DFT3(3, h3r, h3i)
#undef DFT3
#pragma unroll
    for (int j = 0; j < 12; ++j) {
      T[r * RP + b * 12 + j] = make_float2(s_r[j], s_i[j]);
    }
  }
  // NO barrier: phase B reads S rows written by the same wave.

  // ---- Phase B (j-split): thread (r, jq) -> j in {3jq..3jq+2}, all 4 c ----
  // out[12c+j] = sum_b (-i)^{bc} * T_b,  T_b = S[b][j] * W48^{bj}  (4-pt DFT over b)
  {
    const int r = tid >> 2;
    const int jq = tid & 3;
    unsigned* og = out + (size_t)bc * 3072 + r * 48;
#pragma unroll
    for (int k = 0; k < 3; ++k) {
      const int j = 3 * jq + k;
      const float2 S0 = T[r * RP + j];
      const float2 S1 = T[r * RP + 12 + j];
      const float2 S2 = T[r * RP + 24 + j];
      const float2 S3 = T[r * RP + 36 + j];
      // twiddles: j<=11 so 2j,3j < 48 (no modulo)
      const float w1r = COS48[j],     w1i = -SIN48[j];
      const float w2r = COS48[2 * j], w2i = -SIN48[2 * j];
      const float w3r = COS48[3 * j], w3i = -SIN48[3 * j];
      const float T1r = S1.x * w1r - S1.y * w1i, T1i = S1.x * w1i + S1.y * w1r;
      const float T2r = S2.x * w2r - S2.y * w2i, T2i = S2.x * w2i + S2.y * w2r;
      const float T3r = S3.x * w3r - S3.y * w3i, T3i = S3.x * w3i + S3.y * w3r;
      // 4-pt DFT over b, kernel (-i)^{bc}
      const float er = S0.x + T2r, ei = S0.y + T2i;
      const float dr = S0.x - T2r, di = S0.y - T2i;
      const float fr = T1r + T3r, fi = T1i + T3i;
      const float gr = T1r - T3r, gi = T1i - T3i;
      const float s = (j & 1) ? -NORM : NORM;   // (-1)^f = (-1)^j since f = 12c+j
      const float c0r = (er + fr) * s, c0i = (ei + fi) * s;   // c=0
      const float c1r = (dr + gi) * s, c1i = (di - gr) * s;   // c=1: d - i g
      const float c2r = (er - fr) * s, c2i = (ei - fi) * s;   // c=2
      const float c3r = (dr - gi) * s, c3i = (di + gr) * s;   // c=3: d + i g
      og[j]      = bf16_rne(c0i) | (bf16_rne(c0r) << 16);
      og[12 + j] = bf16_rne(c1i) | (bf16_rne(c1r) << 16);
      og[24 + j] = bf16_rne(c2i) | (bf16_rne(c2r) << 16);
      og[36 + j] = bf16_rne(c3i) | (bf16_rne(c3r) << 16);
    }
  }
}

} // namespace

extern "C" void kernel_launch(void* const* d_in, const int* in_sizes, int n_in,
                              void* d_out, int out_size, void* d_ws, size_t ws_size,
                              hipStream_t stream) {
  const float* xr = (const float*)d_in[0];   // dict order: x_real first
  const float* xi = (const float*)d_in[1];
  unsigned* out = (unsigned*)d_out;          // dword = im(bf16) | re(bf16)<<16
  const int nbc = in_sizes[0] / 3072;        // 8192 blocks of (8*4*2*48)
  bd2af_kernel<<<nbc, 256, 0, stream>>>(xr, xi, out, nbc);
}